// Round 1
// baseline (686.384 us; speedup 1.0000x reference)
//
#include <hip/hip_runtime.h>
#include <stdint.h>

#define N_ROWS 65536
#define K_CODES 1024
#define DIM 256

// d_ws layout:
//   [0, 512KB)          : unsigned long long packed_min[N_ROWS]
//   [512KB, 512KB+4KB)  : float e_norm[K_CODES]
//   [516KB, +4B)        : float loss_accum
#define WS_PACKED_OFF 0
#define WS_ENORM_OFF  (N_ROWS * 8)
#define WS_LOSS_OFF   (N_ROWS * 8 + K_CODES * 4)

__device__ __forceinline__ unsigned int forder(float f) {
    unsigned int u = __float_as_uint(f);
    return (u & 0x80000000u) ? ~u : (u | 0x80000000u);
}

// ---- kernel 1: squared norms of embeddings -------------------------------
__global__ __launch_bounds__(64) void vq_enorm(const float* __restrict__ E,
                                               float* __restrict__ enorm) {
    int row = blockIdx.x;
    int lane = threadIdx.x;
    const float4 v = *reinterpret_cast<const float4*>(&E[row * DIM + lane * 4]);
    float s = v.x * v.x + v.y * v.y + v.z * v.z + v.w * v.w;
    #pragma unroll
    for (int m = 32; m >= 1; m >>= 1) s += __shfl_down(s, m, 64);
    if (lane == 0) enorm[row] = s;
}

// ---- kernel 2: fused score-GEMM + argmin merge ---------------------------
// grid (1024, 16): blockIdx.x = row chunk (64 rows), blockIdx.y = code chunk (64 codes)
__global__ __launch_bounds__(256) void vq_argmin(const float* __restrict__ X,
                                                 const float* __restrict__ E,
                                                 const float* __restrict__ enorm,
                                                 unsigned long long* __restrict__ packed) {
    __shared__ float xs[64][36];   // rows x k-slice, padded (stride 144B)
    __shared__ float es[32][68];   // k-major transposed e-tile, padded (stride 272B)

    const int row0 = blockIdx.x * 64;
    const int code0 = blockIdx.y * 64;
    const int tid = threadIdx.x;
    const int tx = tid & 15;       // code group
    const int ty = tid >> 4;       // row group

    float acc[4][4] = {};

    for (int kk = 0; kk < DIM; kk += 32) {
        // stage X slice: 64 rows x 32 cols = 512 float4, 2 per thread
        #pragma unroll
        for (int q = 0; q < 2; ++q) {
            int id = tid + q * 256;
            int r = id >> 3, c4 = id & 7;
            const float4 v = *reinterpret_cast<const float4*>(
                &X[(row0 + r) * DIM + kk + c4 * 4]);
            *reinterpret_cast<float4*>(&xs[r][c4 * 4]) = v;
        }
        // stage E slice transposed to k-major
        #pragma unroll
        for (int q = 0; q < 2; ++q) {
            int id = tid + q * 256;
            int c = id >> 3, k4 = id & 7;
            const float4 v = *reinterpret_cast<const float4*>(
                &E[(code0 + c) * DIM + kk + k4 * 4]);
            es[k4 * 4 + 0][c] = v.x;
            es[k4 * 4 + 1][c] = v.y;
            es[k4 * 4 + 2][c] = v.z;
            es[k4 * 4 + 3][c] = v.w;
        }
        __syncthreads();

        #pragma unroll
        for (int k4 = 0; k4 < 8; ++k4) {
            float a[4][4], b[4][4];
            #pragma unroll
            for (int i = 0; i < 4; ++i) {
                float4 v = *reinterpret_cast<const float4*>(&xs[ty * 4 + i][k4 * 4]);
                a[i][0] = v.x; a[i][1] = v.y; a[i][2] = v.z; a[i][3] = v.w;
            }
            #pragma unroll
            for (int kq = 0; kq < 4; ++kq) {
                float4 v = *reinterpret_cast<const float4*>(&es[k4 * 4 + kq][tx * 4]);
                b[kq][0] = v.x; b[kq][1] = v.y; b[kq][2] = v.z; b[kq][3] = v.w;
            }
            #pragma unroll
            for (int i = 0; i < 4; ++i)
                #pragma unroll
                for (int j = 0; j < 4; ++j)
                    #pragma unroll
                    for (int kq = 0; kq < 4; ++kq)
                        acc[i][j] = fmaf(a[i][kq], b[kq][j], acc[i][j]);
        }
        __syncthreads();
    }

    // score = ||e||^2 - 2 x.e ; per-thread min over its 4 codes, then across tx
    const int codeBase = code0 + tx * 4;
    float en[4];
    #pragma unroll
    for (int j = 0; j < 4; ++j) en[j] = enorm[codeBase + j];

    #pragma unroll
    for (int i = 0; i < 4; ++i) {
        float best = en[0] - 2.0f * acc[i][0];
        int bc = codeBase;
        #pragma unroll
        for (int j = 1; j < 4; ++j) {
            float s = en[j] - 2.0f * acc[i][j];
            if (s < best) { best = s; bc = codeBase + j; }
        }
        // reduce across the 16 tx lanes (xor masks stay inside the 16-group)
        #pragma unroll
        for (int m = 1; m < 16; m <<= 1) {
            float ob = __shfl_xor(best, m, 64);
            int oc = __shfl_xor(bc, m, 64);
            if (ob < best || (ob == best && oc < bc)) { best = ob; bc = oc; }
        }
        if (tx == 0) {
            unsigned long long p =
                ((unsigned long long)forder(best) << 32) | (unsigned int)bc;
            atomicMin(&packed[row0 + ty * 4 + i], p);
        }
    }
}

// ---- kernel 3: gather + STE output + loss partial sums -------------------
__global__ __launch_bounds__(256) void vq_out(const float* __restrict__ X,
                                              const float* __restrict__ E,
                                              const unsigned long long* __restrict__ packed,
                                              float* __restrict__ out,
                                              float* __restrict__ lossAcc) {
    int g = blockIdx.x * 256 + threadIdx.x;   // float4 index, 4194304 total
    int row = g >> 6;                          // 64 float4 per row
    int d4 = g & 63;
    unsigned int code = (unsigned int)(packed[row] & 0xFFFFFFFFull);

    const float4 x = *reinterpret_cast<const float4*>(&X[(size_t)g * 4]);
    const float4 q = *reinterpret_cast<const float4*>(&E[code * DIM + d4 * 4]);

    float4 dif;
    dif.x = q.x - x.x; dif.y = q.y - x.y; dif.z = q.z - x.z; dif.w = q.w - x.w;

    float4 o;
    o.x = x.x + dif.x; o.y = x.y + dif.y; o.z = x.z + dif.z; o.w = x.w + dif.w;
    *reinterpret_cast<float4*>(&out[(size_t)g * 4]) = o;

    float ps = dif.x * dif.x + dif.y * dif.y + dif.z * dif.z + dif.w * dif.w;

    #pragma unroll
    for (int m = 32; m >= 1; m >>= 1) ps += __shfl_down(ps, m, 64);

    __shared__ float red[4];
    int lane = threadIdx.x & 63, wid = threadIdx.x >> 6;
    if (lane == 0) red[wid] = ps;
    __syncthreads();
    if (threadIdx.x == 0)
        atomicAdd(lossAcc, red[0] + red[1] + red[2] + red[3]);
}

// ---- kernel 4: finalize loss ---------------------------------------------
__global__ void vq_finalize(const float* __restrict__ lossAcc,
                            float* __restrict__ out) {
    out[(size_t)N_ROWS * DIM] = 1.25f * lossAcc[0] / (float)((size_t)N_ROWS * DIM);
}

extern "C" void kernel_launch(void* const* d_in, const int* in_sizes, int n_in,
                              void* d_out, int out_size, void* d_ws, size_t ws_size,
                              hipStream_t stream) {
    const float* X = (const float*)d_in[0];     // [65536, 256]
    const float* E = (const float*)d_in[1];     // [1024, 256]
    float* out = (float*)d_out;

    char* ws = (char*)d_ws;
    unsigned long long* packed = (unsigned long long*)(ws + WS_PACKED_OFF);
    float* enorm = (float*)(ws + WS_ENORM_OFF);
    float* lossAcc = (float*)(ws + WS_LOSS_OFF);

    // init: packed mins to UINT64_MAX, loss accumulator to 0 (every call)
    hipMemsetAsync(packed, 0xFF, (size_t)N_ROWS * 8, stream);
    hipMemsetAsync(lossAcc, 0, 4, stream);

    vq_enorm<<<K_CODES, 64, 0, stream>>>(E, enorm);

    dim3 grid2(N_ROWS / 64, K_CODES / 64);
    vq_argmin<<<grid2, 256, 0, stream>>>(X, E, enorm, packed);

    vq_out<<<(N_ROWS * DIM / 4) / 256, 256, 0, stream>>>(X, E, packed, out, lossAcc);

    vq_finalize<<<1, 1, 0, stream>>>(lossAcc, out);
}

// Round 2
// 435.689 us; speedup vs baseline: 1.5754x; 1.5754x over previous
//
#include <hip/hip_runtime.h>
#include <stdint.h>

#define N_ROWS 65536
#define K_CODES 1024
#define DIM 256

typedef unsigned int uint;
typedef unsigned short ushort;
typedef unsigned long long ull;

// d_ws layout:
//   [0, 512K)        packed argmin (ull per row)
//   [512K, +4K)      enorm
//   [+4K, +4K)       loss accumulator (first 4B)
//   [WS_EBF, +1MB)   E split bf16: per code 1024B = [hi 256 bf16 | lo 256 bf16]
#define WS_PACKED_OFF 0
#define WS_ENORM_OFF  (512 * 1024)
#define WS_LOSS_OFF   (WS_ENORM_OFF + 4096)
#define WS_EBF_OFF    (WS_LOSS_OFF + 4096)

typedef __attribute__((ext_vector_type(8))) short bf16x8;
typedef __attribute__((ext_vector_type(4))) float f32x4;

__device__ __forceinline__ ushort f2bf(float f) {
    uint u = __float_as_uint(f);
    return (ushort)((u + 0x7FFFu + ((u >> 16) & 1u)) >> 16);   // RNE
}
__device__ __forceinline__ float bf2f(ushort h) {
    return __uint_as_float(((uint)h) << 16);
}
__device__ __forceinline__ uint forder(float f) {
    uint u = __float_as_uint(f);
    return (u & 0x80000000u) ? ~u : (u | 0x80000000u);
}
__device__ __forceinline__ void gload_lds16(const void* g, void* l) {
    __builtin_amdgcn_global_load_lds(
        (const __attribute__((address_space(1))) void*)g,
        (__attribute__((address_space(3))) void*)l, 16, 0, 0);
}

// ---- prep: split E into bf16 hi/lo rows [hi 512B | lo 512B] ---------------
__global__ __launch_bounds__(256) void vq_prep_e(const float* __restrict__ E,
                                                 ushort* __restrict__ Ebf) {
    int id = blockIdx.x * 256 + threadIdx.x;     // 65536 float4s
    int code = id >> 6, c4 = id & 63;
    float4 v = *reinterpret_cast<const float4*>(E + (size_t)code * DIM + c4 * 4);
    float vx[4] = {v.x, v.y, v.z, v.w};
    ushort h[4], l[4];
    #pragma unroll
    for (int j = 0; j < 4; ++j) {
        h[j] = f2bf(vx[j]);
        l[j] = f2bf(vx[j] - bf2f(h[j]));         // v - fp32(hi) is exact
    }
    uint2 hi, lo;
    hi.x = (uint)h[0] | ((uint)h[1] << 16);
    hi.y = (uint)h[2] | ((uint)h[3] << 16);
    lo.x = (uint)l[0] | ((uint)l[1] << 16);
    lo.y = (uint)l[2] | ((uint)l[3] << 16);
    unsigned char* row = (unsigned char*)Ebf + (size_t)code * 1024;
    *reinterpret_cast<uint2*>(row + c4 * 8) = hi;
    *reinterpret_cast<uint2*>(row + 512 + c4 * 8) = lo;
}

// ---- squared norms of embeddings (fp32 exact) -----------------------------
__global__ __launch_bounds__(64) void vq_enorm(const float* __restrict__ E,
                                               float* __restrict__ enorm) {
    int row = blockIdx.x;
    int lane = threadIdx.x;
    const float4 v = *reinterpret_cast<const float4*>(&E[row * DIM + lane * 4]);
    float s = v.x * v.x + v.y * v.y + v.z * v.z + v.w * v.w;
    #pragma unroll
    for (int m = 32; m >= 1; m >>= 1) s += __shfl_down(s, m, 64);
    if (lane == 0) enorm[row] = s;
}

// ---- fused split-bf16 MFMA score GEMM + argmin ----------------------------
// 128 rows x 128 codes per block, K=256 in 8 steps of 32 fp32 (=32 bf16 hi + 32 lo).
// LDS tile row = 128B: [hi 32 bf16 | lo 32 bf16], XOR-swizzled cb ^= (row&7)<<4.
__global__ __launch_bounds__(256, 2) void vq_mfma(const float* __restrict__ X,
                                                  const ushort* __restrict__ Ebf,
                                                  const float* __restrict__ enorm,
                                                  ull* __restrict__ packed) {
    __shared__ __align__(16) unsigned char smem[65536];  // A[2][16K] | B[2][16K]

    const int bid = blockIdx.x;
    // XCD swizzle: consecutive logical tiles land on one XCD (bid%8 round-robin),
    // so the 8 code-blocks sharing a 128-row X panel hit the same L2.
    const int logical = (bid & 7) * 512 + (bid >> 3);
    const int row0 = (logical >> 3) * 128;
    const int code0 = (logical & 7) * 128;
    const int tid = threadIdx.x;
    const int lane = tid & 63;
    const int w = tid >> 6;
    const int wr = w >> 1, wc = w & 1;   // wave -> 64x64 sub-tile
    const int sr = tid >> 3;             // staging row base (q adds 32)
    const int sc4 = tid & 7;             // staging float4 col
    const int cl = lane & 15;
    const int kq = lane >> 4;

    // epilogue enorm prefetch
    float en[4];
    #pragma unroll
    for (int n = 0; n < 4; ++n)
        en[n] = enorm[code0 + wc * 64 + n * 16 + cl];

    f32x4 acc[4][4];
    #pragma unroll
    for (int m = 0; m < 4; ++m)
        #pragma unroll
        for (int n = 0; n < 4; ++n) {
            f32x4 z = {0.f, 0.f, 0.f, 0.f};
            acc[m][n] = z;
        }

    float4 areg[4];

    auto loadA = [&](int t) {
        const float* src = X + (size_t)row0 * DIM + t * 32;
        #pragma unroll
        for (int q = 0; q < 4; ++q) {
            int r = sr + q * 32;
            areg[q] = *reinterpret_cast<const float4*>(src + (size_t)r * DIM + sc4 * 4);
        }
    };
    auto writeA = [&](int buf) {
        unsigned char* ab = smem + buf * 16384;
        #pragma unroll
        for (int q = 0; q < 4; ++q) {
            int r = sr + q * 32;
            int key = (r & 7) << 4;
            float vx[4] = {areg[q].x, areg[q].y, areg[q].z, areg[q].w};
            ushort h[4], l[4];
            #pragma unroll
            for (int j = 0; j < 4; ++j) {
                h[j] = f2bf(vx[j]);
                l[j] = f2bf(vx[j] - bf2f(h[j]));
            }
            uint2 hi, lo;
            hi.x = (uint)h[0] | ((uint)h[1] << 16);
            hi.y = (uint)h[2] | ((uint)h[3] << 16);
            lo.x = (uint)l[0] | ((uint)l[1] << 16);
            lo.y = (uint)l[2] | ((uint)l[3] << 16);
            *reinterpret_cast<uint2*>(ab + r * 128 + ((sc4 * 8) ^ key)) = hi;
            *reinterpret_cast<uint2*>(ab + r * 128 + ((64 | (sc4 * 8)) ^ key)) = lo;
        }
    };
    auto loadB = [&](int t, int buf) {
        unsigned char* bb = smem + 32768 + buf * 16384;
        #pragma unroll
        for (int i = 0; i < 4; ++i) {
            int o = w * 4096 + i * 1024 + lane * 16;
            int r = o >> 7;
            int cbp = o & 127;
            int cb = cbp ^ ((r & 7) << 4);   // pre-swizzled global source (rule 21)
            int seg = cb >> 6;
            const unsigned char* g = (const unsigned char*)Ebf
                + (size_t)(code0 + r) * 1024 + seg * 512 + t * 64 + (cb & 63);
            gload_lds16(g, bb + w * 4096 + i * 1024);
        }
    };
    auto compute = [&](int buf) {
        const unsigned char* ab = smem + buf * 16384;
        const unsigned char* bb = smem + 32768 + buf * 16384;
        const int key = (cl & 7) << 4;
        bf16x8 aH[4], aL[4], bH[4], bL[4];
        #pragma unroll
        for (int m = 0; m < 4; ++m) {
            int off = (wr * 64 + m * 16 + cl) * 128;
            aH[m] = *reinterpret_cast<const bf16x8*>(ab + off + ((kq * 16) ^ key));
            aL[m] = *reinterpret_cast<const bf16x8*>(ab + off + ((64 | (kq * 16)) ^ key));
        }
        #pragma unroll
        for (int n = 0; n < 4; ++n) {
            int off = (wc * 64 + n * 16 + cl) * 128;
            bH[n] = *reinterpret_cast<const bf16x8*>(bb + off + ((kq * 16) ^ key));
            bL[n] = *reinterpret_cast<const bf16x8*>(bb + off + ((64 | (kq * 16)) ^ key));
        }
        #pragma unroll
        for (int m = 0; m < 4; ++m)
            #pragma unroll
            for (int n = 0; n < 4; ++n) {
                acc[m][n] = __builtin_amdgcn_mfma_f32_16x16x32_bf16(aH[m], bH[n], acc[m][n], 0, 0, 0);
                acc[m][n] = __builtin_amdgcn_mfma_f32_16x16x32_bf16(aL[m], bH[n], acc[m][n], 0, 0, 0);
                acc[m][n] = __builtin_amdgcn_mfma_f32_16x16x32_bf16(aH[m], bL[n], acc[m][n], 0, 0, 0);
            }
    };

    // prologue
    loadA(0);
    loadB(0, 0);
    writeA(0);
    loadA(1);

    for (int t = 0; t < 8; ++t) {
        __syncthreads();                 // buf t ready (compiler drains vm/lgkm)
        compute(t & 1);
        if (t < 7) {
            writeA((t + 1) & 1);         // areg holds data(t+1)
            loadB(t + 1, (t + 1) & 1);
            if (t < 6) loadA(t + 2);     // T14: issue-early, consumed next iter
        }
    }

    // epilogue: per-row argmin; C layout col=lane&15, row=(lane>>4)*4+reg (m89)
    #pragma unroll
    for (int m = 0; m < 4; ++m) {
        #pragma unroll
        for (int r = 0; r < 4; ++r) {
            float best = fmaf(-2.f, acc[m][0][r], en[0]);
            int bc = code0 + wc * 64 + cl;
            #pragma unroll
            for (int n = 1; n < 4; ++n) {
                float s = fmaf(-2.f, acc[m][n][r], en[n]);
                int c = code0 + wc * 64 + n * 16 + cl;
                if (s < best) { best = s; bc = c; }
            }
            #pragma unroll
            for (int mask = 1; mask < 16; mask <<= 1) {
                float ob = __shfl_xor(best, mask, 64);
                int oc = __shfl_xor(bc, mask, 64);
                if (ob < best || (ob == best && oc < bc)) { best = ob; bc = oc; }
            }
            if (cl == 0) {
                int row = row0 + wr * 64 + m * 16 + kq * 4 + r;
                ull p = ((ull)forder(best) << 32) | (uint)bc;
                atomicMin(&packed[row], p);
            }
        }
    }
}

// ---- gather + STE output + loss partial sums ------------------------------
__global__ __launch_bounds__(256) void vq_out(const float* __restrict__ X,
                                              const float* __restrict__ E,
                                              const ull* __restrict__ packed,
                                              float* __restrict__ out,
                                              float* __restrict__ lossAcc) {
    int g = blockIdx.x * 256 + threadIdx.x;
    int row = g >> 6;
    int d4 = g & 63;
    uint code = (uint)(packed[row] & 0xFFFFFFFFull);

    const float4 x = *reinterpret_cast<const float4*>(&X[(size_t)g * 4]);
    const float4 q = *reinterpret_cast<const float4*>(&E[code * DIM + d4 * 4]);

    float4 dif;
    dif.x = q.x - x.x; dif.y = q.y - x.y; dif.z = q.z - x.z; dif.w = q.w - x.w;

    float4 o;
    o.x = x.x + dif.x; o.y = x.y + dif.y; o.z = x.z + dif.z; o.w = x.w + dif.w;
    *reinterpret_cast<float4*>(&out[(size_t)g * 4]) = o;

    float ps = dif.x * dif.x + dif.y * dif.y + dif.z * dif.z + dif.w * dif.w;
    #pragma unroll
    for (int m = 32; m >= 1; m >>= 1) ps += __shfl_down(ps, m, 64);

    __shared__ float red[4];
    int lane = threadIdx.x & 63, wid = threadIdx.x >> 6;
    if (lane == 0) red[wid] = ps;
    __syncthreads();
    if (threadIdx.x == 0)
        atomicAdd(lossAcc, red[0] + red[1] + red[2] + red[3]);
}

__global__ void vq_finalize(const float* __restrict__ lossAcc,
                            float* __restrict__ out) {
    out[(size_t)N_ROWS * DIM] = 1.25f * lossAcc[0] / (float)((size_t)N_ROWS * DIM);
}

extern "C" void kernel_launch(void* const* d_in, const int* in_sizes, int n_in,
                              void* d_out, int out_size, void* d_ws, size_t ws_size,
                              hipStream_t stream) {
    const float* X = (const float*)d_in[0];
    const float* E = (const float*)d_in[1];
    float* out = (float*)d_out;

    char* ws = (char*)d_ws;
    ull* packed = (ull*)(ws + WS_PACKED_OFF);
    float* enorm = (float*)(ws + WS_ENORM_OFF);
    float* lossAcc = (float*)(ws + WS_LOSS_OFF);
    ushort* Ebf = (ushort*)(ws + WS_EBF_OFF);

    hipMemsetAsync(packed, 0xFF, (size_t)N_ROWS * 8, stream);
    hipMemsetAsync(lossAcc, 0, 4, stream);

    vq_prep_e<<<256, 256, 0, stream>>>(E, Ebf);
    vq_enorm<<<K_CODES, 64, 0, stream>>>(E, enorm);

    vq_mfma<<<(N_ROWS / 128) * (K_CODES / 128), 256, 0, stream>>>(X, Ebf, enorm, packed);

    vq_out<<<(N_ROWS * DIM / 4) / 256, 256, 0, stream>>>(X, E, packed, out, lossAcc);

    vq_finalize<<<1, 1, 0, stream>>>(lossAcc, out);
}

// Round 3
// 68.112 us; speedup vs baseline: 10.0772x; 6.3966x over previous
//
#include <hip/hip_runtime.h>
#include <stdint.h>

#define N_ROWS 65536
#define K_CODES 1024
#define DIM 256

typedef unsigned int uint;
typedef unsigned short ushort;
typedef unsigned long long ull;

// d_ws layout:
//   [0, 4K)       loss accumulator (first 4B)
//   [4K, 8K)      enorm[1024] fp32
//   [8K, +512K)   Ebf: bf16(hi) codebook, 512B per code
#define WS_LOSS_OFF  0
#define WS_ENORM_OFF 4096
#define WS_EBF_OFF   8192

typedef __attribute__((ext_vector_type(8))) short bf16x8;
typedef __attribute__((ext_vector_type(4))) float f32x4;

__device__ __forceinline__ ushort f2bf(float f) {
    uint u = __float_as_uint(f);
    return (ushort)((u + 0x7FFFu + ((u >> 16) & 1u)) >> 16);   // RNE
}
__device__ __forceinline__ void gload_lds16(const void* g, void* l) {
    __builtin_amdgcn_global_load_lds(
        (const __attribute__((address_space(1))) void*)g,
        (__attribute__((address_space(3))) void*)l, 16, 0, 0);
}

// ---- prep: E -> bf16 codebook + exact fp32 squared norms ------------------
// 64 consecutive threads (= one wave... 64-aligned group) per code.
__global__ __launch_bounds__(256) void vq_prep(const float* __restrict__ E,
                                               ushort* __restrict__ Ebf,
                                               float* __restrict__ enorm) {
    int id = blockIdx.x * 256 + threadIdx.x;      // 65536 = 1024 codes * 64 f4
    int code = id >> 6, c4 = id & 63;
    float4 v = *reinterpret_cast<const float4*>(E + (size_t)code * DIM + c4 * 4);
    ushort h0 = f2bf(v.x), h1 = f2bf(v.y), h2 = f2bf(v.z), h3 = f2bf(v.w);
    uint2 hi;
    hi.x = (uint)h0 | ((uint)h1 << 16);
    hi.y = (uint)h2 | ((uint)h3 << 16);
    *reinterpret_cast<uint2*>((char*)Ebf + (size_t)code * 512 + c4 * 8) = hi;

    float s = v.x * v.x + v.y * v.y + v.z * v.z + v.w * v.w;
    #pragma unroll
    for (int m = 32; m >= 1; m >>= 1) s += __shfl_down(s, m, 64);
    if (c4 == 0) enorm[code] = s;
}

// ---- fused: bf16 MFMA scores + argmin + gather/STE out + loss -------------
// Block: 128 rows x all 1024 codes. 4 waves x 32 rows. A in registers.
// B: 16 tiles of 64 codes x K=256 bf16 (32KB), double-buffered in LDS.
__global__ __launch_bounds__(256, 2) void vq_main(const float* __restrict__ X,
                                                  const ushort* __restrict__ Ebf,
                                                  const float* __restrict__ enorm,
                                                  const float* __restrict__ E,
                                                  float* __restrict__ out,
                                                  float* __restrict__ lossAcc) {
    __shared__ __align__(16) unsigned char bsm[65536];   // B double buffer
    __shared__ float enormLds[1024];
    __shared__ float xnormLds[128];
    __shared__ int bcLds[128];
    __shared__ float lossSh;

    const int tid = threadIdx.x;
    const int lane = tid & 63;
    const int w = tid >> 6;
    const int cl = lane & 15;
    const int kq = lane >> 4;
    const int row0 = blockIdx.x * 128;

    auto stageB = [&](int tile, int buf) {
        unsigned char* dst = bsm + buf * 32768;
        const unsigned char* src = (const unsigned char*)Ebf + (size_t)(tile * 64) * 512;
        #pragma unroll
        for (int j = 0; j < 8; ++j) {
            int o = j * 4096 + tid * 16;                  // linear LDS dest
            int r = o >> 9;
            int cb = (o & 511) ^ ((r & 7) << 4);          // pre-swizzled source (rule 21)
            gload_lds16(src + (size_t)r * 512 + cb, dst + o);
        }
    };

    stageB(0, 0);

    // enorm -> LDS (4KB)
    *reinterpret_cast<float4*>(&enormLds[tid * 4]) =
        *reinterpret_cast<const float4*>(&enorm[tid * 4]);
    if (tid == 0) lossSh = 0.f;

    // A fragments: global -> reg, bf16 convert in flight, exact ||x||^2
    bf16x8 aF[2][8];
    float nrm0 = 0.f, nrm1 = 0.f;
    #pragma unroll
    for (int m = 0; m < 2; ++m) {
        const float* rp = X + (size_t)(row0 + w * 32 + m * 16 + cl) * DIM;
        #pragma unroll
        for (int t = 0; t < 8; ++t) {
            float4 v0 = *reinterpret_cast<const float4*>(rp + t * 32 + kq * 8);
            float4 v1 = *reinterpret_cast<const float4*>(rp + t * 32 + kq * 8 + 4);
            float e[8] = {v0.x, v0.y, v0.z, v0.w, v1.x, v1.y, v1.z, v1.w};
            bf16x8 f;
            float p = 0.f;
            #pragma unroll
            for (int j = 0; j < 8; ++j) {
                f[j] = (short)f2bf(e[j]);
                p = fmaf(e[j], e[j], p);
            }
            aF[m][t] = f;
            if (m == 0) nrm0 += p; else nrm1 += p;
        }
    }
    nrm0 += __shfl_xor(nrm0, 16, 64); nrm0 += __shfl_xor(nrm0, 32, 64);
    nrm1 += __shfl_xor(nrm1, 16, 64); nrm1 += __shfl_xor(nrm1, 32, 64);
    if (kq == 0) {
        xnormLds[w * 32 + cl] = nrm0;
        xnormLds[w * 32 + 16 + cl] = nrm1;
    }

    float best[2][4];
    int bcode[2][4];
    #pragma unroll
    for (int m = 0; m < 2; ++m)
        #pragma unroll
        for (int r = 0; r < 4; ++r) { best[m][r] = 3.4e38f; bcode[m][r] = 0; }

    for (int t = 0; t < 16; ++t) {
        __syncthreads();                       // buf t&1 staged & visible
        if (t < 15) stageB(t + 1, (t + 1) & 1);

        const unsigned char* bb = bsm + (t & 1) * 32768;
        float en[4];
        #pragma unroll
        for (int n = 0; n < 4; ++n) en[n] = enormLds[t * 64 + n * 16 + cl];

        f32x4 acc[2][4];
        #pragma unroll
        for (int m = 0; m < 2; ++m)
            #pragma unroll
            for (int n = 0; n < 4; ++n) {
                f32x4 z = {0.f, 0.f, 0.f, 0.f};
                acc[m][n] = z;
            }

        #pragma unroll
        for (int ks = 0; ks < 8; ++ks) {
            bf16x8 bf[4];
            #pragma unroll
            for (int n = 0; n < 4; ++n) {
                int r = n * 16 + cl;
                bf[n] = *reinterpret_cast<const bf16x8*>(
                    bb + r * 512 + ((ks * 64 + kq * 16) ^ ((r & 7) << 4)));
            }
            #pragma unroll
            for (int m = 0; m < 2; ++m)
                #pragma unroll
                for (int n = 0; n < 4; ++n)
                    acc[m][n] = __builtin_amdgcn_mfma_f32_16x16x32_bf16(
                        aF[m][ks], bf[n], acc[m][n], 0, 0, 0);
        }

        // fold scores into running argmin (codes ascend -> strict < keeps first)
        #pragma unroll
        for (int m = 0; m < 2; ++m)
            #pragma unroll
            for (int r = 0; r < 4; ++r)
                #pragma unroll
                for (int n = 0; n < 4; ++n) {
                    float s = fmaf(-2.f, acc[m][n][r], en[n]);
                    if (s < best[m][r]) {
                        best[m][r] = s;
                        bcode[m][r] = t * 64 + n * 16 + cl;
                    }
                }
    }

    // reduce across the 16 cl lanes; C-row = m*16 + kq*4 + r (m89 layout)
    float lsum = 0.f;
    #pragma unroll
    for (int m = 0; m < 2; ++m)
        #pragma unroll
        for (int r = 0; r < 4; ++r) {
            float b = best[m][r];
            int c = bcode[m][r];
            #pragma unroll
            for (int mask = 1; mask < 16; mask <<= 1) {
                float ob = __shfl_xor(b, mask, 64);
                int oc = __shfl_xor(c, mask, 64);
                if (ob < b || (ob == b && oc < c)) { b = ob; c = oc; }
            }
            if (cl == 0) {
                int row = w * 32 + m * 16 + kq * 4 + r;
                bcLds[row] = c;
                lsum += xnormLds[row] + b;     // ||x||^2 + ||e||^2 - 2 x.e
            }
        }
    if (cl == 0) atomicAdd(&lossSh, lsum);
    __syncthreads();

    // output: out[row] = E[bc[row]]  (== x + (q - x) to ~3e-7)
    #pragma unroll 8
    for (int i = 0; i < 32; ++i) {
        int g = i * 256 + tid;                 // f4 index within block tile
        int row = g >> 6, c4 = g & 63;
        int code = bcLds[row];
        float4 q = *reinterpret_cast<const float4*>(E + (size_t)code * DIM + c4 * 4);
        *reinterpret_cast<float4*>(out + (size_t)row0 * DIM + g * 4) = q;
    }
    if (tid == 0) atomicAdd(lossAcc, lossSh);
}

__global__ void vq_finalize(const float* __restrict__ lossAcc,
                            float* __restrict__ out) {
    out[(size_t)N_ROWS * DIM] = 1.25f * lossAcc[0] / (float)((size_t)N_ROWS * DIM);
}

extern "C" void kernel_launch(void* const* d_in, const int* in_sizes, int n_in,
                              void* d_out, int out_size, void* d_ws, size_t ws_size,
                              hipStream_t stream) {
    const float* X = (const float*)d_in[0];
    const float* E = (const float*)d_in[1];
    float* out = (float*)d_out;

    char* ws = (char*)d_ws;
    float* lossAcc = (float*)(ws + WS_LOSS_OFF);
    float* enorm = (float*)(ws + WS_ENORM_OFF);
    ushort* Ebf = (ushort*)(ws + WS_EBF_OFF);

    hipMemsetAsync(lossAcc, 0, 4, stream);
    vq_prep<<<256, 256, 0, stream>>>(E, Ebf, enorm);
    vq_main<<<N_ROWS / 128, 256, 0, stream>>>(X, Ebf, enorm, E, out, lossAcc);
    vq_finalize<<<1, 1, 0, stream>>>(lossAcc, out);
}